// Round 6
// baseline (52.493 us; speedup 1.0000x reference)
//
#include <hip/hip_runtime.h>

#define TT 200
#define DD 64
#define BLOCK 256
#define KSH 68      // bf16 halfwords per K row (136 B rows; 8B-aligned, 2-way-free banks)
#define NTILE 13    // ceil(200/16) row-tiles; last tile clamped to t0=184

typedef unsigned short u16;
typedef unsigned int u32;
typedef __attribute__((ext_vector_type(8))) u16 ushort8;
typedef __attribute__((ext_vector_type(8))) short short8v;  // MFMA bf16x8 frag
typedef __attribute__((ext_vector_type(4))) float f32x4;    // MFMA acc

union Frag { uint2 h[2]; short8v v; };

__device__ __forceinline__ float bflo(u32 w) {
    union { u32 u; float f; } v; v.u = w << 16; return v.f;
}
__device__ __forceinline__ float bfhi(u32 w) {
    union { u32 u; float f; } v; v.u = w & 0xFFFF0000u; return v.f;
}
__device__ __forceinline__ float bf2f(u16 h) {
    union { u32 u; float f; } v; v.u = ((u32)h) << 16; return v.f;
}
__device__ __forceinline__ u16 f2bf(float f) {
    union { float f; u32 u; } v; v.f = f;
    return (u16)((v.u + 0x7FFFu + ((v.u >> 16) & 1u)) >> 16);
}
__device__ __forceinline__ u32 cvt_pk_bf16(float lo, float hi) {
    u32 r;
    asm("v_cvt_pk_bf16_f32 %0, %1, %2" : "=v"(r) : "v"(lo), "v"(hi));
    return r;
}
__device__ __forceinline__ float sigmoid_fast(float x) {
    return __builtin_amdgcn_rcpf(1.0f + __expf(-x));
}

__global__ __launch_bounds__(BLOCK, 5) void attn_pool_kernel(
    const float* __restrict__ queries, const float* __restrict__ keys,
    const int* __restrict__ masks, const float* __restrict__ W1,
    const float* __restrict__ b1, const float* __restrict__ W2,
    const float* __restrict__ b2, const float* __restrict__ W3,
    const float* __restrict__ b3, float* __restrict__ out)
{
    __shared__ __align__(16) u16   lds_kh[TT][KSH];   // 27,200 B
    __shared__ __align__(16) u16   lds_cwt[16][KSH];  // 2,176 B; dead after GEMM -> e/part/red alias
    __shared__ __align__(16) u16   lds_s[TT][8];      // 3,200 B  scores bf16 (16B rows)
    __shared__ __align__(16) float lds_qw1[8];        // 32 B     total: 32,608 B -> 5 blocks/CU
    float* lds_e = (float*)&lds_cwt[0][0];                    // [200] f32 (800 B)
    float* part  = (float*)((char*)&lds_cwt[0][0] + 800);     // [4][64] f32 (1024 B)
    float* red   = part + 4 * DD;                             // [4] f32

    const int b = blockIdx.x;
    const int tid = threadIdx.x;
    const int wave = tid >> 6;
    const int lane = tid & 63;

    // ---- prefetch masks ----
    int m0 = 0, m1 = 0;
    if (tid < 100) {
        m0 = masks[b * TT + tid];
        m1 = masks[b * TT + tid + 100];
    }

    // ---- stage K: fp32 global -> bf16 LDS (keys read exactly once) ----
    const float4* kp = (const float4*)(keys + (size_t)b * TT * DD);
#pragma unroll
    for (int k = 0; k < 13; ++k) {
        int i = tid + (k << 8);
        if (i < TT * DD / 4) {
            float4 v = kp[i];
            u32 r0 = cvt_pk_bf16(v.x, v.y);
            u32 r1 = cvt_pk_bf16(v.z, v.w);
            int row = i >> 4, col = (i & 15) << 2;
            uint2 wpack; wpack.x = r0; wpack.y = r1;
            *(uint2*)&lds_kh[row][col] = wpack;
        }
    }

    // ---- fold weights -> CW^T bf16: cwt[j][d] = (W1b-W1c)[d][j] + q[d]*W1d[d][j] ----
#pragma unroll
    for (int f = tid; f < DD * 8; f += BLOCK) {
        int d = f & 63, j = f >> 6;
        float qd = queries[b * DD + d];
        float v = W1[(64 + d) * 8 + j] - W1[(128 + d) * 8 + j]
                + qd * W1[(192 + d) * 8 + j];
        lds_cwt[j][d] = f2bf(v);
    }

    // ---- qw1[j] = b1[j] + sum_d q[d]*(W1a+W1c)[d][j]  (wave 0) ----
    if (wave == 0) {
        float qd = queries[b * DD + lane];
        const float4* wa = (const float4*)&W1[lane * 8];
        const float4* wc = (const float4*)&W1[(128 + lane) * 8];
        float4 a0 = wa[0], a1 = wa[1], c0 = wc[0], c1 = wc[1];
        float p8[8];
        p8[0] = qd * (a0.x + c0.x); p8[1] = qd * (a0.y + c0.y);
        p8[2] = qd * (a0.z + c0.z); p8[3] = qd * (a0.w + c0.w);
        p8[4] = qd * (a1.x + c1.x); p8[5] = qd * (a1.y + c1.y);
        p8[6] = qd * (a1.z + c1.z); p8[7] = qd * (a1.w + c1.w);
#pragma unroll
        for (int j = 0; j < 8; ++j) {
#pragma unroll
            for (int off = 32; off; off >>= 1)
                p8[j] += __shfl_xor(p8[j], off, 64);
        }
        if (lane == 0) {
#pragma unroll
            for (int j = 0; j < 8; ++j) lds_qw1[j] = p8[j] + b1[j];
        }
    }
    __syncthreads();   // B1: kh, cwt, qw1 ready

    // ---- score GEMM via MFMA: S = K @ CW ----
    {
        const int r = lane & 15, g = lane >> 4;
        Frag bf0, bf1;
        bf0.h[0] = *(const uint2*)&lds_cwt[r][g * 8];
        bf0.h[1] = *(const uint2*)&lds_cwt[r][g * 8 + 4];
        bf1.h[0] = *(const uint2*)&lds_cwt[r][32 + g * 8];
        bf1.h[1] = *(const uint2*)&lds_cwt[r][32 + g * 8 + 4];
        for (int tile = wave; tile < NTILE; tile += 4) {
            int t0 = tile << 4;
            if (t0 > TT - 16) t0 = TT - 16;     // 184: rows 184-191 dup-computed (identical)
            Frag a0, a1;
            a0.h[0] = *(const uint2*)&lds_kh[t0 + r][g * 8];
            a0.h[1] = *(const uint2*)&lds_kh[t0 + r][g * 8 + 4];
            a1.h[0] = *(const uint2*)&lds_kh[t0 + r][32 + g * 8];
            a1.h[1] = *(const uint2*)&lds_kh[t0 + r][32 + g * 8 + 4];
            f32x4 acc = {0.0f, 0.0f, 0.0f, 0.0f};
            acc = __builtin_amdgcn_mfma_f32_16x16x32_bf16(a0.v, bf0.v, acc, 0, 0, 0);
            acc = __builtin_amdgcn_mfma_f32_16x16x32_bf16(a1.v, bf1.v, acc, 0, 0, 0);
            if (r < 8) {                        // D: col(j)=lane&15, row(t)=g*4+reg
                const int rr = t0 + (g << 2);
                lds_s[rr + 0][r] = f2bf(acc[0]);
                lds_s[rr + 1][r] = f2bf(acc[1]);
                lds_s[rr + 2][r] = f2bf(acc[2]);
                lds_s[rr + 3][r] = f2bf(acc[3]);
            }
        }
    }
    __syncthreads();   // B2: S ready; cwt dead

    // ---- MLP tail: threads 0..99, rows (t, t+100) ----
    if (tid < 100) {
        const int t0 = tid, t1 = tid + 100;
        ushort8 sa8 = *(const ushort8*)&lds_s[t0][0];
        ushort8 sb8 = *(const ushort8*)&lds_s[t1][0];
        float qw[8];
        *(float4*)&qw[0] = *(const float4*)&lds_qw1[0];
        *(float4*)&qw[4] = *(const float4*)&lds_qw1[4];
        float h1a[8], h1b[8];
#pragma unroll
        for (int j = 0; j < 8; ++j) {
            h1a[j] = sigmoid_fast(bf2f(sa8[j]) + qw[j]);
            h1b[j] = sigmoid_fast(bf2f(sb8[j]) + qw[j]);
        }
        float sa = b3[0], sb = b3[0];
#pragma unroll
        for (int c = 0; c < 4; ++c) {
            float ha = b2[c], hb = b2[c];
#pragma unroll
            for (int j = 0; j < 8; ++j) {
                float w2 = W2[j * 4 + c];
                ha = fmaf(h1a[j], w2, ha);
                hb = fmaf(h1b[j], w2, hb);
            }
            float w3 = W3[c];
            sa = fmaf(sigmoid_fast(ha), w3, sa);
            sb = fmaf(sigmoid_fast(hb), w3, sb);
        }
        // no-max softmax: |score| bounded (<~0.5), masked -> exactly 0
        lds_e[t0] = m0 ? __expf(sa) : 0.0f;
        lds_e[t1] = m1 ? __expf(sb) : 0.0f;
    }
    __syncthreads();   // B3: e ready

    // ---- PV from bf16 LDS (0-conflict): lane = (half, d-pair) ----
    const int half = lane >> 5;
    const int dp = lane & 31;
    const int d0 = dp << 1;
    const int tbase = (wave << 1) + half;   // 0..7
    float acc0 = 0.0f, acc1 = 0.0f;
#pragma unroll
    for (int i = 0; i < 25; ++i) {
        const int t = tbase + (i << 3);
        u32 kw = *(const u32*)&lds_kh[t][d0];
        float e = lds_e[t];
        acc0 = fmaf(e, bflo(kw), acc0);
        acc1 = fmaf(e, bfhi(kw), acc1);
    }
    acc0 += __shfl_xor(acc0, 32, 64);
    acc1 += __shfl_xor(acc1, 32, 64);
    if (half == 0) {
        float2 wpack; wpack.x = acc0; wpack.y = acc1;
        *(float2*)&part[wave * DD + d0] = wpack;
    }
    __syncthreads();   // B4: partials ready

    // ---- epilogue (wave 0): e-sum + combine + store ----
    if (wave == 0) {
        float s = lds_e[lane] + lds_e[64 + lane] + lds_e[128 + lane];
        if (lane < 8) s += lds_e[192 + lane];
#pragma unroll
        for (int off = 32; off; off >>= 1) s += __shfl_xor(s, off, 64);
        float r = part[lane] + part[DD + lane] + part[2 * DD + lane] + part[3 * DD + lane];
        out[b * DD + lane] = r / s;
    }
}

extern "C" void kernel_launch(void* const* d_in, const int* in_sizes, int n_in,
                              void* d_out, int out_size, void* d_ws, size_t ws_size,
                              hipStream_t stream) {
    const float* queries = (const float*)d_in[0];
    const float* keys    = (const float*)d_in[1];
    const int*   masks   = (const int*)d_in[2];
    const float* W1      = (const float*)d_in[3];
    const float* b1      = (const float*)d_in[4];
    const float* W2      = (const float*)d_in[5];
    const float* b2      = (const float*)d_in[6];
    const float* W3      = (const float*)d_in[7];
    const float* b3      = (const float*)d_in[8];
    float* out = (float*)d_out;

    const int B = in_sizes[0] / DD;  // 4096
    attn_pool_kernel<<<B, BLOCK, 0, stream>>>(queries, keys, masks, W1, b1, W2, b2, W3, b3, out);
}